// Round 11
// baseline (739.583 us; speedup 1.0000x reference)
//
#include <hip/hip_runtime.h>
#include <hip/hip_bf16.h>
#include <math.h>

#define E_N 200000
#define R_N 1000
#define D 128
#define NT 200000
#define NE (2*NT)
#define KDIM 300
#define KP 320
#define BETA 0.3f
#define ALPHA_L 0.2f
#define SCB 1024
#define RPB 64           // rows per block in name GEMM (16 per wave)
#define CHUNK_SHORTS (5 * 8 * 64 * 8)   // 5 K-steps of frag-order W = 40KB
#define NBLK 196         // ceil(E_N / SCB)

typedef __attribute__((ext_vector_type(8))) short short8;
typedef __attribute__((ext_vector_type(4))) float f32x4v;
typedef __attribute__((ext_vector_type(4))) unsigned short ushort4v;

__device__ inline short bfc(float f) {
  __hip_bfloat16 b = __float2bfloat16(f);
  return *reinterpret_cast<short*>(&b);
}
__device__ inline float b2f(unsigned short u) {
  return __uint_as_float((unsigned)u << 16);
}

// ---------------------------------------------------------------------------
// Fused: zero relDeg/rowDeg + pack W[300][128] -> bf16 fragment-order (KP=320)
// ---------------------------------------------------------------------------
__global__ __launch_bounds__(256) void k_prep_zero(
    const float* __restrict__ W, short* __restrict__ WtG,
    int4* __restrict__ relDeg, int4* __restrict__ rowDeg)
{
  int e = blockIdx.x * 256 + threadIdx.x;
  const int4 z = {0, 0, 0, 0};
  if (e < R_N / 4) relDeg[e] = z;
  if (e < E_N / 4) rowDeg[e] = z;
  if (e < D * KP) {
    int j = e & 7;
    int l = (e >> 3) & 63;
    int fi = e >> 9;
    int s = fi >> 3, f = fi & 7;
    int k = s * 32 + (l >> 4) * 8 + j;
    int c = f * 16 + (l & 15);
    float v = (k < KDIM) ? W[(size_t)k * D + c] : 0.f;
    WtG[e] = bfc(v);
  }
}

// ---------------------------------------------------------------------------
// name16 = bf16(A[E,300] @ W + b). MEASUREMENT: REP repeats of full body.
// ---------------------------------------------------------------------------
template <int REP>
__global__ __launch_bounds__(256, 4) void k_name_mfma(
    const float* __restrict__ A, const short* __restrict__ WtG,
    const float* __restrict__ b, short* __restrict__ out16)
{
  __shared__ short Wt[CHUNK_SHORTS];    // 40960 B

  const int tid = threadIdx.x;
  const int wid = tid >> 6;
  const int l   = tid & 63;
  const int lc  = l & 15;
  const int kb  = l >> 4;
  const int rowbase = blockIdx.x * RPB + wid * 16;

  const float* pa = A + (size_t)(rowbase + lc) * KDIM + kb * 8;

  f32x4v acc[8];

  for (int rep = 0; rep < REP; rep++) {
#pragma unroll
    for (int f = 0; f < 8; f++) acc[f] = (f32x4v){0.f, 0.f, 0.f, 0.f};

    float4 buf0[2], buf1[2];
    buf0[0] = *(const float4*)(pa + 0);
    buf0[1] = *(const float4*)(pa + 4);
    buf1[0] = *(const float4*)(pa + 32);
    buf1[1] = *(const float4*)(pa + 36);

#pragma unroll
    for (int c = 0; c < 2; c++) {
      __syncthreads();   // protect Wt before restage (also rep boundary)
      {
        const uint4* src = (const uint4*)(WtG + c * CHUNK_SHORTS);
        uint4* dst = (uint4*)Wt;
#pragma unroll
        for (int i = 0; i < 10; i++) dst[i * 256 + tid] = src[i * 256 + tid];
      }
      __syncthreads();

#pragma unroll
      for (int s5 = 0; s5 < 5; s5++) {
        const int s = c * 5 + s5;
        float4* cb = (s & 1) ? buf1 : buf0;
        short8 af;
        af[0] = bfc(cb[0].x); af[1] = bfc(cb[0].y);
        af[2] = bfc(cb[0].z); af[3] = bfc(cb[0].w);
        af[4] = bfc(cb[1].x); af[5] = bfc(cb[1].y);
        af[6] = bfc(cb[1].z); af[7] = bfc(cb[1].w);
        if (s <= 7) {
          if (s == 7) {
            float4 z = {0.f, 0.f, 0.f, 0.f};
            cb[0] = (kb <= 1) ? *(const float4*)(pa + 288) : z;
            cb[1] = (kb == 0) ? *(const float4*)(pa + 292) : z;
          } else {
            int k = 32 * (s + 2);
            cb[0] = *(const float4*)(pa + k);
            cb[1] = *(const float4*)(pa + k + 4);
          }
        }
#pragma unroll
        for (int f = 0; f < 8; f++) {
          const short8 bf = *(const short8*)((const char*)Wt + (((s5 * 8 + f) << 6) + l) * 16);
          acc[f] = __builtin_amdgcn_mfma_f32_16x16x32_bf16(af, bf, acc[f], 0, 0, 0);
        }
      }
    }
  }

  float bv[8];
#pragma unroll
  for (int f = 0; f < 8; f++) bv[f] = b[f * 16 + lc];

#pragma unroll
  for (int ii = 0; ii < 4; ii++) {
    int row = rowbase + kb * 4 + ii;
#pragma unroll
    for (int f = 0; f < 8; f++)
      out16[(size_t)row * D + f * 16 + lc] = bfc(acc[f][ii] + bv[f]);
  }
}

// ---------------------------------------------------------------------------
// CSR build
// ---------------------------------------------------------------------------
__global__ __launch_bounds__(256) void k_hist(
    const int* __restrict__ th, const int* __restrict__ tr,
    const int* __restrict__ tt,
    int* __restrict__ relDeg, int* __restrict__ rowDeg)
{
  int i = blockIdx.x * 256 + threadIdx.x;
  if (i >= NT) return;
  atomicAdd(&relDeg[tr[i]], 1);
  atomicAdd(&rowDeg[th[i]], 1);
  atomicAdd(&rowDeg[tt[i]], 1);
}

__global__ __launch_bounds__(SCB) void k_scan_both(
    const int* __restrict__ rowDeg, int* __restrict__ rowOff,
    const int* __restrict__ relDeg, int* __restrict__ relOff,
    int* __restrict__ part)
{
  __shared__ int buf[SCB];
  bool isRel = (blockIdx.x == NBLK);
  const int* in = isRel ? relDeg : rowDeg;
  int* outp     = isRel ? relOff : rowOff;
  int n         = isRel ? R_N : E_N;
  int base      = isRel ? 0 : blockIdx.x * SCB;
  int i = base + threadIdx.x;
  int v = (i < n) ? in[i] : 0;
  buf[threadIdx.x] = v;
  __syncthreads();
  for (int off = 1; off < SCB; off <<= 1) {
    int add = (threadIdx.x >= off) ? buf[threadIdx.x - off] : 0;
    __syncthreads();
    buf[threadIdx.x] += add;
    __syncthreads();
  }
  if (i < n) outp[i] = buf[threadIdx.x] - v;
  if (!isRel && threadIdx.x == SCB - 1) part[blockIdx.x] = buf[SCB - 1];
}

__global__ __launch_bounds__(SCB) void k_scan_block(
    const int* __restrict__ in, int* __restrict__ out,
    int* __restrict__ part, int n)
{
  __shared__ int buf[SCB];
  int i = blockIdx.x * SCB + threadIdx.x;
  int v = (i < n) ? in[i] : 0;
  buf[threadIdx.x] = v;
  __syncthreads();
  for (int off = 1; off < SCB; off <<= 1) {
    int add = (threadIdx.x >= off) ? buf[threadIdx.x - off] : 0;
    __syncthreads();
    buf[threadIdx.x] += add;
    __syncthreads();
  }
  if (i < n) out[i] = buf[threadIdx.x] - v;
  if (threadIdx.x == SCB - 1 && part) part[blockIdx.x] = buf[SCB - 1];
}

__global__ __launch_bounds__(SCB) void k_scan_add(
    int* __restrict__ out, const int* __restrict__ part, int n)
{
  int i = blockIdx.x * SCB + threadIdx.x;
  if (i < n) out[i] += part[blockIdx.x];
}

__global__ __launch_bounds__(256) void k_scatter(
    const int* __restrict__ th, const int* __restrict__ tr,
    const int* __restrict__ tt,
    int* __restrict__ relOff, int* __restrict__ rowOff,
    int* __restrict__ relIdx, unsigned* __restrict__ edgeCR)
{
  int i = blockIdx.x * 256 + threadIdx.x;
  if (i >= NT) return;
  int h = th[i], r = tr[i], t = tt[i];
  int p = atomicAdd(&relOff[r], 1);
  relIdx[p] = i;
  int pf = atomicAdd(&rowOff[h], 1);
  edgeCR[pf] = (unsigned)t | ((unsigned)r << 18);
  int pb = atomicAdd(&rowOff[t], 1);
  edgeCR[pb] = (unsigned)h | ((unsigned)r << 18);
}

// ---------------------------------------------------------------------------
// per-relation sums + mix GEMM -> packed bf16 abR. MEASUREMENT: REP repeats.
// ---------------------------------------------------------------------------
template <int REP>
__global__ __launch_bounds__(256) void k_rel_fused(
    const short* __restrict__ ent16,
    const int* __restrict__ th, const int* __restrict__ tt,
    const int* __restrict__ relIdx, const int* __restrict__ relOff,
    const float* __restrict__ wL, const float* __restrict__ wR,
    const float* __restrict__ watt,
    unsigned short* __restrict__ abR)
{
  __shared__ float bufH[8][128];
  __shared__ float bufT[8][128];
  __shared__ float red[2][128];
  int r = blockIdx.x;
  int start = (r == 0) ? 0 : relOff[r - 1];
  int end   = relOff[r];
  int g = threadIdx.x >> 5, q = threadIdx.x & 31;

  for (int rep = 0; rep < REP; rep++) {
    float4 aH = {0.f, 0.f, 0.f, 0.f}, aT = {0.f, 0.f, 0.f, 0.f};
    int j = start + g;
    for (; j + 8 < end; j += 16) {
      int i0 = relIdx[j];
      int i1 = relIdx[j + 8];
      ushort4v eh0 = *(const ushort4v*)&ent16[(size_t)th[i0] * D + q * 4];
      ushort4v et0 = *(const ushort4v*)&ent16[(size_t)tt[i0] * D + q * 4];
      ushort4v eh1 = *(const ushort4v*)&ent16[(size_t)th[i1] * D + q * 4];
      ushort4v et1 = *(const ushort4v*)&ent16[(size_t)tt[i1] * D + q * 4];
      aH.x += b2f(eh0[0]) + b2f(eh1[0]); aH.y += b2f(eh0[1]) + b2f(eh1[1]);
      aH.z += b2f(eh0[2]) + b2f(eh1[2]); aH.w += b2f(eh0[3]) + b2f(eh1[3]);
      aT.x += b2f(et0[0]) + b2f(et1[0]); aT.y += b2f(et0[1]) + b2f(et1[1]);
      aT.z += b2f(et0[2]) + b2f(et1[2]); aT.w += b2f(et0[3]) + b2f(et1[3]);
    }
    if (j < end) {
      int i = relIdx[j];
      ushort4v eh = *(const ushort4v*)&ent16[(size_t)th[i] * D + q * 4];
      ushort4v et = *(const ushort4v*)&ent16[(size_t)tt[i] * D + q * 4];
      aH.x += b2f(eh[0]); aH.y += b2f(eh[1]); aH.z += b2f(eh[2]); aH.w += b2f(eh[3]);
      aT.x += b2f(et[0]); aT.y += b2f(et[1]); aT.z += b2f(et[2]); aT.w += b2f(et[3]);
    }
    *(float4*)&bufH[g][q * 4] = aH;
    *(float4*)&bufT[g][q * 4] = aT;
    __syncthreads();

    int side = threadIdx.x >> 7;
    int d = threadIdx.x & 127;
    float s = 0.f;
    if (side == 0) {
#pragma unroll
      for (int g2 = 0; g2 < 8; g2++) s += bufH[g2][d];
    } else {
#pragma unroll
      for (int g2 = 0; g2 < 8; g2++) s += bufT[g2][d];
    }
    red[side][d] = s;
    __syncthreads();

    int cntv = end - start;
    float inv = cntv ? 1.f / (float)cntv : 0.f;
    const float* w = side ? wR : wL;
    float acc = 0.f;
#pragma unroll 8
    for (int k = 0; k < D; k++) acc = fmaf(red[side][k], w[k * D + d], acc);
    float rv = fmaxf(acc * inv, 0.f);
    abR[(size_t)r * 256 + side * 128 + d] =
        (unsigned short)bfc(rv * watt[side * 128 + d]);
  }
}

// ---------------------------------------------------------------------------
// fused edge attention + aggregation + finalize. MEASUREMENT: REP repeats
// with per-rep opaque pointers (blocks cross-rep load CSE; rule #17).
// ---------------------------------------------------------------------------
template <bool ENT_IS_BASE, bool WF32, int REP>
__global__ __launch_bounds__(256) void k_row_edge(
    const short* __restrict__ ent16, const short* __restrict__ base16,
    const unsigned short* __restrict__ abR,
    const int* __restrict__ rowOff, const unsigned* __restrict__ edgeCR,
    float* __restrict__ outf, short* __restrict__ out16)
{
  int gg = blockIdx.x * 256 + threadIdx.x;
  int row = gg >> 5;
  int q = gg & 31;
  if (row >= E_N) return;
  int start = (row == 0) ? 0 : rowOff[row - 1];
  int end   = rowOff[row];

  ushort4v bu = *(const ushort4v*)&base16[(size_t)row * D + q * 4];
  float4 b4;
  b4.x = b2f(bu[0]); b4.y = b2f(bu[1]); b4.z = b2f(bu[2]); b4.w = b2f(bu[3]);
  float4 er;
  if (ENT_IS_BASE) {
    er = b4;
  } else {
    ushort4v e = *(const ushort4v*)&ent16[(size_t)row * D + q * 4];
    er.x = b2f(e[0]); er.y = b2f(e[1]); er.z = b2f(e[2]); er.w = b2f(e[3]);
  }

  float4 acc;
  float rowsum;

  for (int rep = 0; rep < REP; rep++) {
    const short* ent16p = ent16;
    const unsigned short* abRp = abR;
    asm volatile("" : "+s"(ent16p), "+s"(abRp));   // opaque per rep
    acc = (float4){0.f, 0.f, 0.f, 0.f};
    rowsum = 0.f;

    int j = start;
    for (; j + 1 < end; j += 2) {
      unsigned cr0 = edgeCR[j];
      unsigned cr1 = edgeCR[j + 1];
      int col0 = cr0 & 0x3FFFF, rel0 = cr0 >> 18;
      int col1 = cr1 & 0x3FFFF, rel1 = cr1 >> 18;
      ushort4v e0 = *(const ushort4v*)&ent16p[(size_t)col0 * D + q * 4];
      ushort4v e1 = *(const ushort4v*)&ent16p[(size_t)col1 * D + q * 4];
      ushort4v a0u = *(const ushort4v*)&abRp[(size_t)rel0 * 256 + q * 4];
      ushort4v c0u = *(const ushort4v*)&abRp[(size_t)rel0 * 256 + 128 + q * 4];
      ushort4v a1u = *(const ushort4v*)&abRp[(size_t)rel1 * 256 + q * 4];
      ushort4v c1u = *(const ushort4v*)&abRp[(size_t)rel1 * 256 + 128 + q * 4];
      float4 ec0, ec1;
      ec0.x = b2f(e0[0]); ec0.y = b2f(e0[1]); ec0.z = b2f(e0[2]); ec0.w = b2f(e0[3]);
      ec1.x = b2f(e1[0]); ec1.y = b2f(e1[1]); ec1.z = b2f(e1[2]); ec1.w = b2f(e1[3]);
      float p0 = er.x * b2f(a0u[0]) + er.y * b2f(a0u[1])
               + er.z * b2f(a0u[2]) + er.w * b2f(a0u[3])
               + ec0.x * b2f(c0u[0]) + ec0.y * b2f(c0u[1])
               + ec0.z * b2f(c0u[2]) + ec0.w * b2f(c0u[3]);
      float p1 = er.x * b2f(a1u[0]) + er.y * b2f(a1u[1])
               + er.z * b2f(a1u[2]) + er.w * b2f(a1u[3])
               + ec1.x * b2f(c1u[0]) + ec1.y * b2f(c1u[1])
               + ec1.z * b2f(c1u[2]) + ec1.w * b2f(c1u[3]);
#pragma unroll
      for (int m = 16; m >= 1; m >>= 1) {
        p0 += __shfl_xor(p0, m, 64);
        p1 += __shfl_xor(p1, m, 64);
      }
      float l0 = (p0 >= 0.f) ? p0 : ALPHA_L * p0;
      float l1 = (p1 >= 0.f) ? p1 : ALPHA_L * p1;
      float att0 = __expf(-l0);
      float att1 = __expf(-l1);
      acc.x = fmaf(att0, ec0.x, acc.x); acc.y = fmaf(att0, ec0.y, acc.y);
      acc.z = fmaf(att0, ec0.z, acc.z); acc.w = fmaf(att0, ec0.w, acc.w);
      acc.x = fmaf(att1, ec1.x, acc.x); acc.y = fmaf(att1, ec1.y, acc.y);
      acc.z = fmaf(att1, ec1.z, acc.z); acc.w = fmaf(att1, ec1.w, acc.w);
      rowsum += att0 + att1;
    }
    if (j < end) {
      unsigned cr = edgeCR[j];
      int col = cr & 0x3FFFF, rel = cr >> 18;
      ushort4v e = *(const ushort4v*)&ent16p[(size_t)col * D + q * 4];
      ushort4v au = *(const ushort4v*)&abRp[(size_t)rel * 256 + q * 4];
      ushort4v cu = *(const ushort4v*)&abRp[(size_t)rel * 256 + 128 + q * 4];
      float4 ec;
      ec.x = b2f(e[0]); ec.y = b2f(e[1]); ec.z = b2f(e[2]); ec.w = b2f(e[3]);
      float p = er.x * b2f(au[0]) + er.y * b2f(au[1])
              + er.z * b2f(au[2]) + er.w * b2f(au[3])
              + ec.x * b2f(cu[0]) + ec.y * b2f(cu[1])
              + ec.z * b2f(cu[2]) + ec.w * b2f(cu[3]);
#pragma unroll
      for (int m = 16; m >= 1; m >>= 1) p += __shfl_xor(p, m, 64);
      float lk = (p >= 0.f) ? p : ALPHA_L * p;
      float att = __expf(-lk);
      acc.x = fmaf(att, ec.x, acc.x); acc.y = fmaf(att, ec.y, acc.y);
      acc.z = fmaf(att, ec.z, acc.z); acc.w = fmaf(att, ec.w, acc.w);
      rowsum += att;
    }
  }

  float inv = (rowsum == 0.f) ? 0.f : 1.f / rowsum;
  float4 o;
  o.x = b4.x + BETA * fmaxf(acc.x * inv, 0.f);
  o.y = b4.y + BETA * fmaxf(acc.y * inv, 0.f);
  o.z = b4.z + BETA * fmaxf(acc.z * inv, 0.f);
  o.w = b4.w + BETA * fmaxf(acc.w * inv, 0.f);
  if (WF32) {
    *(float4*)&outf[(size_t)row * D + q * 4] = o;
  } else {
    ushort4v u;
    u[0] = (unsigned short)bfc(o.x);
    u[1] = (unsigned short)bfc(o.y);
    u[2] = (unsigned short)bfc(o.z);
    u[3] = (unsigned short)bfc(o.w);
    *(ushort4v*)&out16[(size_t)row * D + q * 4] = u;
  }
}

// ---------------------------------------------------------------------------
extern "C" void kernel_launch(void* const* d_in, const int* in_sizes, int n_in,
                              void* d_out, int out_size, void* d_ws, size_t ws_size,
                              hipStream_t stream)
{
  const float* embed = (const float*)d_in[0];
  const float* wname = (const float*)d_in[1];
  const float* bname = (const float*)d_in[2];
  const float* wL    = (const float*)d_in[3];
  const float* wR    = (const float*)d_in[4];
  const float* watt  = (const float*)d_in[5];
  const int*   th    = (const int*)d_in[6];
  const int*   tr    = (const int*)d_in[7];
  const int*   tt    = (const int*)d_in[8];
  float* out = (float*)d_out;

  char* ws = (char*)d_ws;
  size_t off = 0;
  auto alloc = [&](size_t bytes) -> void* {
    void* p = ws + off;
    off = (off + bytes + 255) & ~(size_t)255;
    return p;
  };
  short*          name16 = (short*)alloc((size_t)E_N * D * 2);
  short*          gat16  = (short*)alloc((size_t)E_N * D * 2);
  unsigned short* abR    = (unsigned short*)alloc((size_t)R_N * 256 * 2);
  int*            relDeg = (int*)alloc((size_t)R_N * 4);
  int*            relOff = (int*)alloc((size_t)R_N * 4);
  int*            rowDeg = (int*)alloc((size_t)E_N * 4);
  int*            rowOff = (int*)alloc((size_t)E_N * 4);
  int*            relIdx = (int*)alloc((size_t)NT * 4);
  unsigned*       edgeCR = (unsigned*)alloc((size_t)NE * 4);
  int*            part   = (int*)alloc((size_t)256 * 4);
  short*          WtG    = (short*)alloc((size_t)D * KP * 2);

  // prep (W pack + deg zero), then name GEMM (x3 internal repeat: MEASURE)
  k_prep_zero<<<NBLK, 256, 0, stream>>>(wname, WtG, (int4*)relDeg, (int4*)rowDeg);
  k_name_mfma<3><<<E_N / RPB, 256, 0, stream>>>(embed, WtG, bname, name16);

  // CSR build (layer-invariant)
  k_hist<<<(NT + 255) / 256, 256, 0, stream>>>(th, tr, tt, relDeg, rowDeg);
  k_scan_both<<<NBLK + 1, SCB, 0, stream>>>(rowDeg, rowOff, relDeg, relOff, part);
  k_scan_block<<<1, SCB, 0, stream>>>(part, part, nullptr, NBLK);
  k_scan_add<<<NBLK, SCB, 0, stream>>>(rowOff, part, E_N);
  k_scatter<<<(NT + 255) / 256, 256, 0, stream>>>(th, tr, tt, relOff, rowOff,
                                                  relIdx, edgeCR);

  // layer 1 (rel x4, edge x3 internal repeats: MEASURE)
  k_rel_fused<4><<<R_N, 256, 0, stream>>>(name16, th, tt, relIdx, relOff,
                                          wL, wR, watt, abR);
  k_row_edge<true, false, 3><<<(E_N * 32) / 256, 256, 0, stream>>>(
      name16, name16, abR, rowOff, edgeCR, nullptr, gat16);

  // layer 2
  k_rel_fused<4><<<R_N, 256, 0, stream>>>(gat16, th, tt, relIdx, relOff,
                                          wL, wR, watt, abR);
  k_row_edge<false, true, 3><<<(E_N * 32) / 256, 256, 0, stream>>>(
      gat16, name16, abR, rowOff, edgeCR, out, nullptr);
}

// Round 12
// 385.988 us; speedup vs baseline: 1.9161x; 1.9161x over previous
//
#include <hip/hip_runtime.h>
#include <hip/hip_bf16.h>
#include <math.h>

#define E_N 200000
#define R_N 1000
#define D 128
#define NT 200000
#define NE (2*NT)
#define KDIM 300
#define KP 320
#define BETA 0.3f
#define ALPHA_L 0.2f
#define RPB 64           // rows per block in name GEMM (16 per wave)
#define CHUNK_SHORTS (5 * 8 * 64 * 8)   // 5 K-steps of frag-order W = 40KB
#define ROW_BLOCKS 782   // ceil(E_N/256)
#define REL_BLOCKS 4     // ceil(R_N/256)

typedef __attribute__((ext_vector_type(8))) short short8;
typedef __attribute__((ext_vector_type(4))) float f32x4v;
typedef __attribute__((ext_vector_type(4))) unsigned short ushort4v;

__device__ inline short bfc(float f) {
  __hip_bfloat16 b = __float2bfloat16(f);
  return *reinterpret_cast<short*>(&b);
}
__device__ inline float b2f(unsigned short u) {
  return __uint_as_float((unsigned)u << 16);
}

// ---------------------------------------------------------------------------
// Fused: zero relDeg/rowDeg/cursors + pack W -> bf16 fragment-order (KP=320)
// ---------------------------------------------------------------------------
__global__ __launch_bounds__(256) void k_prep_zero(
    const float* __restrict__ W, short* __restrict__ WtG,
    int4* __restrict__ relDeg, int4* __restrict__ rowDeg,
    int* __restrict__ ctr)
{
  int e = blockIdx.x * 256 + threadIdx.x;
  const int4 z = {0, 0, 0, 0};
  if (e < R_N / 4) relDeg[e] = z;
  if (e < E_N / 4) rowDeg[e] = z;
  if (e < 2) ctr[e] = 0;
  if (e < D * KP) {
    int j = e & 7;
    int l = (e >> 3) & 63;
    int fi = e >> 9;
    int s = fi >> 3, f = fi & 7;
    int k = s * 32 + (l >> 4) * 8 + j;
    int c = f * 16 + (l & 15);
    float v = (k < KDIM) ? W[(size_t)k * D + c] : 0.f;
    WtG[e] = bfc(v);
  }
}

// ---------------------------------------------------------------------------
// name16 = bf16(A[E,300] @ W + b). 4 waves x 16 rows; W LDS-chunked (40KB x2);
// A prefetched 2 K-steps deep. Grid 3125 exact.
// ---------------------------------------------------------------------------
__global__ __launch_bounds__(256, 4) void k_name_mfma(
    const float* __restrict__ A, const short* __restrict__ WtG,
    const float* __restrict__ b, short* __restrict__ out16)
{
  __shared__ short Wt[CHUNK_SHORTS];    // 40960 B

  const int tid = threadIdx.x;
  const int wid = tid >> 6;
  const int l   = tid & 63;
  const int lc  = l & 15;
  const int kb  = l >> 4;
  const int rowbase = blockIdx.x * RPB + wid * 16;

  f32x4v acc[8];
#pragma unroll
  for (int f = 0; f < 8; f++) acc[f] = (f32x4v){0.f, 0.f, 0.f, 0.f};

  const float* pa = A + (size_t)(rowbase + lc) * KDIM + kb * 8;

  float4 buf0[2], buf1[2];
  buf0[0] = *(const float4*)(pa + 0);
  buf0[1] = *(const float4*)(pa + 4);
  buf1[0] = *(const float4*)(pa + 32);
  buf1[1] = *(const float4*)(pa + 36);

#pragma unroll
  for (int c = 0; c < 2; c++) {
    if (c == 1) __syncthreads();
    {
      const uint4* src = (const uint4*)(WtG + c * CHUNK_SHORTS);
      uint4* dst = (uint4*)Wt;
#pragma unroll
      for (int i = 0; i < 10; i++) dst[i * 256 + tid] = src[i * 256 + tid];
    }
    __syncthreads();

#pragma unroll
    for (int s5 = 0; s5 < 5; s5++) {
      const int s = c * 5 + s5;
      float4* cb = (s & 1) ? buf1 : buf0;
      short8 af;
      af[0] = bfc(cb[0].x); af[1] = bfc(cb[0].y);
      af[2] = bfc(cb[0].z); af[3] = bfc(cb[0].w);
      af[4] = bfc(cb[1].x); af[5] = bfc(cb[1].y);
      af[6] = bfc(cb[1].z); af[7] = bfc(cb[1].w);
      if (s <= 7) {
        if (s == 7) {
          float4 z = {0.f, 0.f, 0.f, 0.f};
          cb[0] = (kb <= 1) ? *(const float4*)(pa + 288) : z;
          cb[1] = (kb == 0) ? *(const float4*)(pa + 292) : z;
        } else {
          int k = 32 * (s + 2);
          cb[0] = *(const float4*)(pa + k);
          cb[1] = *(const float4*)(pa + k + 4);
        }
      }
#pragma unroll
      for (int f = 0; f < 8; f++) {
        const short8 bf = *(const short8*)((const char*)Wt + (((s5 * 8 + f) << 6) + l) * 16);
        acc[f] = __builtin_amdgcn_mfma_f32_16x16x32_bf16(af, bf, acc[f], 0, 0, 0);
      }
    }
  }

  float bv[8];
#pragma unroll
  for (int f = 0; f < 8; f++) bv[f] = b[f * 16 + lc];

#pragma unroll
  for (int ii = 0; ii < 4; ii++) {
    int row = rowbase + kb * 4 + ii;
#pragma unroll
    for (int f = 0; f < 8; f++)
      out16[(size_t)row * D + f * 16 + lc] = bfc(acc[f][ii] + bv[f]);
  }
}

// ---------------------------------------------------------------------------
// degree histogram
// ---------------------------------------------------------------------------
__global__ __launch_bounds__(256) void k_hist(
    const int* __restrict__ th, const int* __restrict__ tr,
    const int* __restrict__ tt,
    int* __restrict__ relDeg, int* __restrict__ rowDeg)
{
  int i = blockIdx.x * 256 + threadIdx.x;
  if (i >= NT) return;
  atomicAdd(&relDeg[tr[i]], 1);
  atomicAdd(&rowDeg[th[i]], 1);
  atomicAdd(&rowDeg[tt[i]], 1);
}

// ---------------------------------------------------------------------------
// scan-free CSR allocation: per-block 256-wide scan + 1 atomic per block.
// Row ranges are disjoint+contiguous but NOT in row order (irrelevant).
// blocks [0,782): rows; blocks [782,786): relations.
// ---------------------------------------------------------------------------
__global__ __launch_bounds__(256) void k_alloc(
    const int* __restrict__ rowDeg, const int* __restrict__ relDeg,
    int2* __restrict__ rowSD, int2* __restrict__ relSD,
    int* __restrict__ rowPos, int* __restrict__ relPos,
    int* __restrict__ ctr)
{
  __shared__ int sbuf[256];
  __shared__ int sbase;
  bool isRel = (blockIdx.x >= ROW_BLOCKS);
  int idx = (isRel ? (blockIdx.x - ROW_BLOCKS) : blockIdx.x) * 256 + threadIdx.x;
  int n = isRel ? R_N : E_N;
  const int* deg = isRel ? relDeg : rowDeg;
  int d = (idx < n) ? deg[idx] : 0;
  sbuf[threadIdx.x] = d;
  __syncthreads();
  for (int off = 1; off < 256; off <<= 1) {
    int v = (threadIdx.x >= off) ? sbuf[threadIdx.x - off] : 0;
    __syncthreads();
    sbuf[threadIdx.x] += v;
    __syncthreads();
  }
  int incl = sbuf[threadIdx.x];
  if (threadIdx.x == 255) sbase = atomicAdd(&ctr[isRel ? 1 : 0], incl);
  __syncthreads();
  int start = sbase + incl - d;
  if (idx < n) {
    if (isRel) { relSD[idx] = make_int2(start, d); relPos[idx] = start; }
    else       { rowSD[idx] = make_int2(start, d); rowPos[idx] = start; }
  }
}

// ---------------------------------------------------------------------------
// scatter into allocated ranges
// ---------------------------------------------------------------------------
__global__ __launch_bounds__(256) void k_scatter(
    const int* __restrict__ th, const int* __restrict__ tr,
    const int* __restrict__ tt,
    int* __restrict__ relPos, int* __restrict__ rowPos,
    int* __restrict__ relIdx, unsigned* __restrict__ edgeCR)
{
  int i = blockIdx.x * 256 + threadIdx.x;
  if (i >= NT) return;
  int h = th[i], r = tr[i], t = tt[i];
  int p = atomicAdd(&relPos[r], 1);
  relIdx[p] = i;
  int pf = atomicAdd(&rowPos[h], 1);
  edgeCR[pf] = (unsigned)t | ((unsigned)r << 18);
  int pb = atomicAdd(&rowPos[t], 1);
  edgeCR[pb] = (unsigned)h | ((unsigned)r << 18);
}

// ---------------------------------------------------------------------------
// per-relation sums (bf16 gathers, 2x unrolled) + mix GEMM -> packed bf16 abR
// ---------------------------------------------------------------------------
__global__ __launch_bounds__(256) void k_rel_fused(
    const short* __restrict__ ent16,
    const int* __restrict__ th, const int* __restrict__ tt,
    const int* __restrict__ relIdx, const int2* __restrict__ relSD,
    const float* __restrict__ wL, const float* __restrict__ wR,
    const float* __restrict__ watt,
    unsigned short* __restrict__ abR)
{
  __shared__ float bufH[8][128];
  __shared__ float bufT[8][128];
  __shared__ float red[2][128];
  int r = blockIdx.x;
  int2 sd = relSD[r];
  int start = sd.x;
  int end   = sd.x + sd.y;
  int g = threadIdx.x >> 5, q = threadIdx.x & 31;

  float4 aH = {0.f, 0.f, 0.f, 0.f}, aT = {0.f, 0.f, 0.f, 0.f};
  int j = start + g;
  for (; j + 8 < end; j += 16) {
    int i0 = relIdx[j];
    int i1 = relIdx[j + 8];
    ushort4v eh0 = *(const ushort4v*)&ent16[(size_t)th[i0] * D + q * 4];
    ushort4v et0 = *(const ushort4v*)&ent16[(size_t)tt[i0] * D + q * 4];
    ushort4v eh1 = *(const ushort4v*)&ent16[(size_t)th[i1] * D + q * 4];
    ushort4v et1 = *(const ushort4v*)&ent16[(size_t)tt[i1] * D + q * 4];
    aH.x += b2f(eh0[0]) + b2f(eh1[0]); aH.y += b2f(eh0[1]) + b2f(eh1[1]);
    aH.z += b2f(eh0[2]) + b2f(eh1[2]); aH.w += b2f(eh0[3]) + b2f(eh1[3]);
    aT.x += b2f(et0[0]) + b2f(et1[0]); aT.y += b2f(et0[1]) + b2f(et1[1]);
    aT.z += b2f(et0[2]) + b2f(et1[2]); aT.w += b2f(et0[3]) + b2f(et1[3]);
  }
  if (j < end) {
    int i = relIdx[j];
    ushort4v eh = *(const ushort4v*)&ent16[(size_t)th[i] * D + q * 4];
    ushort4v et = *(const ushort4v*)&ent16[(size_t)tt[i] * D + q * 4];
    aH.x += b2f(eh[0]); aH.y += b2f(eh[1]); aH.z += b2f(eh[2]); aH.w += b2f(eh[3]);
    aT.x += b2f(et[0]); aT.y += b2f(et[1]); aT.z += b2f(et[2]); aT.w += b2f(et[3]);
  }
  *(float4*)&bufH[g][q * 4] = aH;
  *(float4*)&bufT[g][q * 4] = aT;
  __syncthreads();

  int side = threadIdx.x >> 7;
  int d = threadIdx.x & 127;
  float s = 0.f;
  if (side == 0) {
#pragma unroll
    for (int g2 = 0; g2 < 8; g2++) s += bufH[g2][d];
  } else {
#pragma unroll
    for (int g2 = 0; g2 < 8; g2++) s += bufT[g2][d];
  }
  red[side][d] = s;
  __syncthreads();

  int cntv = sd.y;
  float inv = cntv ? 1.f / (float)cntv : 0.f;
  const float* w = side ? wR : wL;
  float acc = 0.f;
#pragma unroll 8
  for (int k = 0; k < D; k++) acc = fmaf(red[side][k], w[k * D + d], acc);
  float rv = fmaxf(acc * inv, 0.f);
  abR[(size_t)r * 256 + side * 128 + d] =
      (unsigned short)bfc(rv * watt[side * 128 + d]);
}

// ---------------------------------------------------------------------------
// fused edge attention + aggregation + finalize; bf16 reads incl. abR.
// ---------------------------------------------------------------------------
template <bool ENT_IS_BASE, bool WF32>
__global__ __launch_bounds__(256) void k_row_edge(
    const short* __restrict__ ent16, const short* __restrict__ base16,
    const unsigned short* __restrict__ abR,
    const int2* __restrict__ rowSD, const unsigned* __restrict__ edgeCR,
    float* __restrict__ outf, short* __restrict__ out16)
{
  int gg = blockIdx.x * 256 + threadIdx.x;
  int row = gg >> 5;
  int q = gg & 31;
  if (row >= E_N) return;
  int2 sd = rowSD[row];
  int start = sd.x;
  int end   = sd.x + sd.y;

  ushort4v bu = *(const ushort4v*)&base16[(size_t)row * D + q * 4];
  float4 b4;
  b4.x = b2f(bu[0]); b4.y = b2f(bu[1]); b4.z = b2f(bu[2]); b4.w = b2f(bu[3]);
  float4 er;
  if (ENT_IS_BASE) {
    er = b4;
  } else {
    ushort4v e = *(const ushort4v*)&ent16[(size_t)row * D + q * 4];
    er.x = b2f(e[0]); er.y = b2f(e[1]); er.z = b2f(e[2]); er.w = b2f(e[3]);
  }
  float4 acc = {0.f, 0.f, 0.f, 0.f};
  float rowsum = 0.f;

  int j = start;
  for (; j + 1 < end; j += 2) {
    unsigned cr0 = edgeCR[j];
    unsigned cr1 = edgeCR[j + 1];
    int col0 = cr0 & 0x3FFFF, rel0 = cr0 >> 18;
    int col1 = cr1 & 0x3FFFF, rel1 = cr1 >> 18;
    ushort4v e0 = *(const ushort4v*)&ent16[(size_t)col0 * D + q * 4];
    ushort4v e1 = *(const ushort4v*)&ent16[(size_t)col1 * D + q * 4];
    ushort4v a0u = *(const ushort4v*)&abR[(size_t)rel0 * 256 + q * 4];
    ushort4v c0u = *(const ushort4v*)&abR[(size_t)rel0 * 256 + 128 + q * 4];
    ushort4v a1u = *(const ushort4v*)&abR[(size_t)rel1 * 256 + q * 4];
    ushort4v c1u = *(const ushort4v*)&abR[(size_t)rel1 * 256 + 128 + q * 4];
    float4 ec0, ec1;
    ec0.x = b2f(e0[0]); ec0.y = b2f(e0[1]); ec0.z = b2f(e0[2]); ec0.w = b2f(e0[3]);
    ec1.x = b2f(e1[0]); ec1.y = b2f(e1[1]); ec1.z = b2f(e1[2]); ec1.w = b2f(e1[3]);
    float p0 = er.x * b2f(a0u[0]) + er.y * b2f(a0u[1])
             + er.z * b2f(a0u[2]) + er.w * b2f(a0u[3])
             + ec0.x * b2f(c0u[0]) + ec0.y * b2f(c0u[1])
             + ec0.z * b2f(c0u[2]) + ec0.w * b2f(c0u[3]);
    float p1 = er.x * b2f(a1u[0]) + er.y * b2f(a1u[1])
             + er.z * b2f(a1u[2]) + er.w * b2f(a1u[3])
             + ec1.x * b2f(c1u[0]) + ec1.y * b2f(c1u[1])
             + ec1.z * b2f(c1u[2]) + ec1.w * b2f(c1u[3]);
#pragma unroll
    for (int m = 16; m >= 1; m >>= 1) {
      p0 += __shfl_xor(p0, m, 64);
      p1 += __shfl_xor(p1, m, 64);
    }
    float l0 = (p0 >= 0.f) ? p0 : ALPHA_L * p0;
    float l1 = (p1 >= 0.f) ? p1 : ALPHA_L * p1;
    float att0 = __expf(-l0);
    float att1 = __expf(-l1);
    acc.x = fmaf(att0, ec0.x, acc.x); acc.y = fmaf(att0, ec0.y, acc.y);
    acc.z = fmaf(att0, ec0.z, acc.z); acc.w = fmaf(att0, ec0.w, acc.w);
    acc.x = fmaf(att1, ec1.x, acc.x); acc.y = fmaf(att1, ec1.y, acc.y);
    acc.z = fmaf(att1, ec1.z, acc.z); acc.w = fmaf(att1, ec1.w, acc.w);
    rowsum += att0 + att1;
  }
  if (j < end) {
    unsigned cr = edgeCR[j];
    int col = cr & 0x3FFFF, rel = cr >> 18;
    ushort4v e = *(const ushort4v*)&ent16[(size_t)col * D + q * 4];
    ushort4v au = *(const ushort4v*)&abR[(size_t)rel * 256 + q * 4];
    ushort4v cu = *(const ushort4v*)&abR[(size_t)rel * 256 + 128 + q * 4];
    float4 ec;
    ec.x = b2f(e[0]); ec.y = b2f(e[1]); ec.z = b2f(e[2]); ec.w = b2f(e[3]);
    float p = er.x * b2f(au[0]) + er.y * b2f(au[1])
            + er.z * b2f(au[2]) + er.w * b2f(au[3])
            + ec.x * b2f(cu[0]) + ec.y * b2f(cu[1])
            + ec.z * b2f(cu[2]) + ec.w * b2f(cu[3]);
#pragma unroll
    for (int m = 16; m >= 1; m >>= 1) p += __shfl_xor(p, m, 64);
    float lk = (p >= 0.f) ? p : ALPHA_L * p;
    float att = __expf(-lk);
    acc.x = fmaf(att, ec.x, acc.x); acc.y = fmaf(att, ec.y, acc.y);
    acc.z = fmaf(att, ec.z, acc.z); acc.w = fmaf(att, ec.w, acc.w);
    rowsum += att;
  }
  float inv = (rowsum == 0.f) ? 0.f : 1.f / rowsum;
  float4 o;
  o.x = b4.x + BETA * fmaxf(acc.x * inv, 0.f);
  o.y = b4.y + BETA * fmaxf(acc.y * inv, 0.f);
  o.z = b4.z + BETA * fmaxf(acc.z * inv, 0.f);
  o.w = b4.w + BETA * fmaxf(acc.w * inv, 0.f);
  if (WF32) {
    *(float4*)&outf[(size_t)row * D + q * 4] = o;
  } else {
    ushort4v u;
    u[0] = (unsigned short)bfc(o.x);
    u[1] = (unsigned short)bfc(o.y);
    u[2] = (unsigned short)bfc(o.z);
    u[3] = (unsigned short)bfc(o.w);
    *(ushort4v*)&out16[(size_t)row * D + q * 4] = u;
  }
}

// ---------------------------------------------------------------------------
extern "C" void kernel_launch(void* const* d_in, const int* in_sizes, int n_in,
                              void* d_out, int out_size, void* d_ws, size_t ws_size,
                              hipStream_t stream)
{
  const float* embed = (const float*)d_in[0];
  const float* wname = (const float*)d_in[1];
  const float* bname = (const float*)d_in[2];
  const float* wL    = (const float*)d_in[3];
  const float* wR    = (const float*)d_in[4];
  const float* watt  = (const float*)d_in[5];
  const int*   th    = (const int*)d_in[6];
  const int*   tr    = (const int*)d_in[7];
  const int*   tt    = (const int*)d_in[8];
  float* out = (float*)d_out;

  char* ws = (char*)d_ws;
  size_t off = 0;
  auto alloc = [&](size_t bytes) -> void* {
    void* p = ws + off;
    off = (off + bytes + 255) & ~(size_t)255;
    return p;
  };
  short*          name16 = (short*)alloc((size_t)E_N * D * 2);
  short*          gat16  = (short*)alloc((size_t)E_N * D * 2);
  unsigned short* abR    = (unsigned short*)alloc((size_t)R_N * 256 * 2);
  int*            relDeg = (int*)alloc((size_t)R_N * 4);
  int*            rowDeg = (int*)alloc((size_t)E_N * 4);
  int2*           rowSD  = (int2*)alloc((size_t)E_N * 8);
  int2*           relSD  = (int2*)alloc((size_t)R_N * 8);
  int*            rowPos = (int*)alloc((size_t)E_N * 4);
  int*            relPos = (int*)alloc((size_t)R_N * 4);
  int*            relIdx = (int*)alloc((size_t)NT * 4);
  unsigned*       edgeCR = (unsigned*)alloc((size_t)NE * 4);
  int*            ctr    = (int*)alloc((size_t)2 * 4);
  short*          WtG    = (short*)alloc((size_t)D * KP * 2);

  // prep (W pack + zero), then name GEMM
  k_prep_zero<<<ROW_BLOCKS / 4 + 1, 256, 0, stream>>>(
      wname, WtG, (int4*)relDeg, (int4*)rowDeg, ctr);
  k_name_mfma<<<E_N / RPB, 256, 0, stream>>>(embed, WtG, bname, name16);

  // CSR build: hist -> scan-free alloc -> scatter
  k_hist<<<(NT + 255) / 256, 256, 0, stream>>>(th, tr, tt, relDeg, rowDeg);
  k_alloc<<<ROW_BLOCKS + REL_BLOCKS, 256, 0, stream>>>(
      rowDeg, relDeg, rowSD, relSD, rowPos, relPos, ctr);
  k_scatter<<<(NT + 255) / 256, 256, 0, stream>>>(th, tr, tt, relPos, rowPos,
                                                  relIdx, edgeCR);

  // layer 1: ent = base = name16, emit gat16
  k_rel_fused<<<R_N, 256, 0, stream>>>(name16, th, tt, relIdx, relSD,
                                       wL, wR, watt, abR);
  k_row_edge<true, false><<<(E_N * 32) / 256, 256, 0, stream>>>(
      name16, name16, abR, rowSD, edgeCR, nullptr, gat16);

  // layer 2: ent = gat16, base = name16, emit f32 out
  k_rel_fused<<<R_N, 256, 0, stream>>>(gat16, th, tt, relIdx, relSD,
                                       wL, wR, watt, abR);
  k_row_edge<false, true><<<(E_N * 32) / 256, 256, 0, stream>>>(
      gat16, name16, abR, rowSD, edgeCR, out, nullptr);
}

// Round 13
// 370.420 us; speedup vs baseline: 1.9966x; 1.0420x over previous
//
#include <hip/hip_runtime.h>
#include <hip/hip_bf16.h>
#include <math.h>

#define E_N 200000
#define R_N 1000
#define D 128
#define NT 200000
#define NE (2*NT)
#define KDIM 300
#define KP 320
#define BETA 0.3f
#define ALPHA_L 0.2f
#define RPB 64           // rows per block in name GEMM (16 per wave)
#define CHUNK_SHORTS (2 * 8 * 64 * 8)   // 2 K-steps of frag-order W = 16KB
#define NAME_BLOCKS (E_N / RPB)         // 3125
#define HIST_BLOCKS 782                 // ceil(NT/256)
#define ROW_BLOCKS 782   // ceil(E_N/256)
#define REL_BLOCKS 4     // ceil(R_N/256)

typedef __attribute__((ext_vector_type(8))) short short8;
typedef __attribute__((ext_vector_type(4))) float f32x4v;
typedef __attribute__((ext_vector_type(4))) unsigned short ushort4v;

__device__ inline short bfc(float f) {
  __hip_bfloat16 b = __float2bfloat16(f);
  return *reinterpret_cast<short*>(&b);
}
__device__ inline float b2f(unsigned short u) {
  return __uint_as_float((unsigned)u << 16);
}

// ---------------------------------------------------------------------------
// Fused: zero relDeg/rowDeg/cursors + pack W -> bf16 fragment-order (KP=320)
// ---------------------------------------------------------------------------
__global__ __launch_bounds__(256) void k_prep_zero(
    const float* __restrict__ W, short* __restrict__ WtG,
    int4* __restrict__ relDeg, int4* __restrict__ rowDeg,
    int* __restrict__ ctr)
{
  int e = blockIdx.x * 256 + threadIdx.x;
  const int4 z = {0, 0, 0, 0};
  if (e < R_N / 4) relDeg[e] = z;
  if (e < E_N / 4) rowDeg[e] = z;
  if (e < 2) ctr[e] = 0;
  if (e < D * KP) {
    int j = e & 7;
    int l = (e >> 3) & 63;
    int fi = e >> 9;
    int s = fi >> 3, f = fi & 7;
    int k = s * 32 + (l >> 4) * 8 + j;
    int c = f * 16 + (l & 15);
    float v = (k < KDIM) ? W[(size_t)k * D + c] : 0.f;
    WtG[e] = bfc(v);
  }
}

// ---------------------------------------------------------------------------
// name16 = bf16(A[E,300] @ W + b), PLUS degree histogram in trailing blocks.
// 4 waves x 16 rows; W LDS-chunked 16KB x5 -> 8 blocks/CU, 32 waves/CU.
// A prefetched 2 K-steps deep. blocks >= NAME_BLOCKS do the triple histogram.
// ---------------------------------------------------------------------------
__global__ __launch_bounds__(256, 8) void k_name_hist(
    const float* __restrict__ A, const short* __restrict__ WtG,
    const float* __restrict__ b, short* __restrict__ out16,
    const int* __restrict__ th, const int* __restrict__ tr,
    const int* __restrict__ tt,
    int* __restrict__ relDeg, int* __restrict__ rowDeg)
{
  __shared__ short Wt[CHUNK_SHORTS];    // 16384 B

  if (blockIdx.x >= NAME_BLOCKS) {      // histogram blocks (independent work)
    int i = (blockIdx.x - NAME_BLOCKS) * 256 + threadIdx.x;
    if (i < NT) {
      atomicAdd(&relDeg[tr[i]], 1);
      atomicAdd(&rowDeg[th[i]], 1);
      atomicAdd(&rowDeg[tt[i]], 1);
    }
    return;
  }

  const int tid = threadIdx.x;
  const int wid = tid >> 6;
  const int l   = tid & 63;
  const int lc  = l & 15;
  const int kb  = l >> 4;
  const int rowbase = blockIdx.x * RPB + wid * 16;

  f32x4v acc[8];
#pragma unroll
  for (int f = 0; f < 8; f++) acc[f] = (f32x4v){0.f, 0.f, 0.f, 0.f};

  const float* pa = A + (size_t)(rowbase + lc) * KDIM + kb * 8;

  // 2-deep register pipeline: buf0 = even K-step, buf1 = odd
  float4 buf0[2], buf1[2];
  buf0[0] = *(const float4*)(pa + 0);
  buf0[1] = *(const float4*)(pa + 4);
  buf1[0] = *(const float4*)(pa + 32);
  buf1[1] = *(const float4*)(pa + 36);

#pragma unroll
  for (int c = 0; c < 5; c++) {
    if (c > 0) __syncthreads();   // protect Wt before restage
    {  // stage chunk c (16KB linear: 4 x 256 x 16B)
      const uint4* src = (const uint4*)(WtG + c * CHUNK_SHORTS);
      uint4* dst = (uint4*)Wt;
#pragma unroll
      for (int i = 0; i < 4; i++) dst[i * 256 + tid] = src[i * 256 + tid];
    }
    __syncthreads();

#pragma unroll
    for (int s2 = 0; s2 < 2; s2++) {
      const int s = c * 2 + s2;
      float4* cb = (s & 1) ? buf1 : buf0;   // compile-time (unrolled s)
      short8 af;
      af[0] = bfc(cb[0].x); af[1] = bfc(cb[0].y);
      af[2] = bfc(cb[0].z); af[3] = bfc(cb[0].w);
      af[4] = bfc(cb[1].x); af[5] = bfc(cb[1].y);
      af[6] = bfc(cb[1].z); af[7] = bfc(cb[1].w);
      // refill this buffer with K-step s+2
      if (s <= 7) {
        if (s == 7) {   // step 9: k0=288, valid k<300 only
          float4 z = {0.f, 0.f, 0.f, 0.f};
          cb[0] = (kb <= 1) ? *(const float4*)(pa + 288) : z;
          cb[1] = (kb == 0) ? *(const float4*)(pa + 292) : z;
        } else {
          int k = 32 * (s + 2);
          cb[0] = *(const float4*)(pa + k);
          cb[1] = *(const float4*)(pa + k + 4);
        }
      }
#pragma unroll
      for (int f = 0; f < 8; f++) {
        const short8 bf = *(const short8*)((const char*)Wt + (((s2 * 8 + f) << 6) + l) * 16);
        acc[f] = __builtin_amdgcn_mfma_f32_16x16x32_bf16(af, bf, acc[f], 0, 0, 0);
      }
    }
  }

  float bv[8];
#pragma unroll
  for (int f = 0; f < 8; f++) bv[f] = b[f * 16 + lc];

  // epilogue: C frag layout col = lane&15, row = kb*4 + ii
#pragma unroll
  for (int ii = 0; ii < 4; ii++) {
    int row = rowbase + kb * 4 + ii;
#pragma unroll
    for (int f = 0; f < 8; f++)
      out16[(size_t)row * D + f * 16 + lc] = bfc(acc[f][ii] + bv[f]);
  }
}

// ---------------------------------------------------------------------------
// scan-free CSR allocation: per-block 256-wide scan + 1 atomic per block.
// blocks [0,782): rows; blocks [782,786): relations.
// ---------------------------------------------------------------------------
__global__ __launch_bounds__(256) void k_alloc(
    const int* __restrict__ rowDeg, const int* __restrict__ relDeg,
    int2* __restrict__ rowSD, int2* __restrict__ relSD,
    int* __restrict__ rowPos, int* __restrict__ relPos,
    int* __restrict__ ctr)
{
  __shared__ int sbuf[256];
  __shared__ int sbase;
  bool isRel = (blockIdx.x >= ROW_BLOCKS);
  int idx = (isRel ? (blockIdx.x - ROW_BLOCKS) : blockIdx.x) * 256 + threadIdx.x;
  int n = isRel ? R_N : E_N;
  const int* deg = isRel ? relDeg : rowDeg;
  int d = (idx < n) ? deg[idx] : 0;
  sbuf[threadIdx.x] = d;
  __syncthreads();
  for (int off = 1; off < 256; off <<= 1) {
    int v = (threadIdx.x >= off) ? sbuf[threadIdx.x - off] : 0;
    __syncthreads();
    sbuf[threadIdx.x] += v;
    __syncthreads();
  }
  int incl = sbuf[threadIdx.x];
  if (threadIdx.x == 255) sbase = atomicAdd(&ctr[isRel ? 1 : 0], incl);
  __syncthreads();
  int start = sbase + incl - d;
  if (idx < n) {
    if (isRel) { relSD[idx] = make_int2(start, d); relPos[idx] = start; }
    else       { rowSD[idx] = make_int2(start, d); rowPos[idx] = start; }
  }
}

// ---------------------------------------------------------------------------
// scatter into allocated ranges
// ---------------------------------------------------------------------------
__global__ __launch_bounds__(256) void k_scatter(
    const int* __restrict__ th, const int* __restrict__ tr,
    const int* __restrict__ tt,
    int* __restrict__ relPos, int* __restrict__ rowPos,
    int* __restrict__ relIdx, unsigned* __restrict__ edgeCR)
{
  int i = blockIdx.x * 256 + threadIdx.x;
  if (i >= NT) return;
  int h = th[i], r = tr[i], t = tt[i];
  int p = atomicAdd(&relPos[r], 1);
  relIdx[p] = i;
  int pf = atomicAdd(&rowPos[h], 1);
  edgeCR[pf] = (unsigned)t | ((unsigned)r << 18);
  int pb = atomicAdd(&rowPos[t], 1);
  edgeCR[pb] = (unsigned)h | ((unsigned)r << 18);
}

// ---------------------------------------------------------------------------
// per-relation sums (bf16 gathers, 2x unrolled) + mix GEMM -> packed bf16 abR
// ---------------------------------------------------------------------------
__global__ __launch_bounds__(256) void k_rel_fused(
    const short* __restrict__ ent16,
    const int* __restrict__ th, const int* __restrict__ tt,
    const int* __restrict__ relIdx, const int2* __restrict__ relSD,
    const float* __restrict__ wL, const float* __restrict__ wR,
    const float* __restrict__ watt,
    unsigned short* __restrict__ abR)
{
  __shared__ float bufH[8][128];
  __shared__ float bufT[8][128];
  __shared__ float red[2][128];
  int r = blockIdx.x;
  int2 sd = relSD[r];
  int start = sd.x;
  int end   = sd.x + sd.y;
  int g = threadIdx.x >> 5, q = threadIdx.x & 31;

  float4 aH = {0.f, 0.f, 0.f, 0.f}, aT = {0.f, 0.f, 0.f, 0.f};
  int j = start + g;
  for (; j + 8 < end; j += 16) {
    int i0 = relIdx[j];
    int i1 = relIdx[j + 8];
    ushort4v eh0 = *(const ushort4v*)&ent16[(size_t)th[i0] * D + q * 4];
    ushort4v et0 = *(const ushort4v*)&ent16[(size_t)tt[i0] * D + q * 4];
    ushort4v eh1 = *(const ushort4v*)&ent16[(size_t)th[i1] * D + q * 4];
    ushort4v et1 = *(const ushort4v*)&ent16[(size_t)tt[i1] * D + q * 4];
    aH.x += b2f(eh0[0]) + b2f(eh1[0]); aH.y += b2f(eh0[1]) + b2f(eh1[1]);
    aH.z += b2f(eh0[2]) + b2f(eh1[2]); aH.w += b2f(eh0[3]) + b2f(eh1[3]);
    aT.x += b2f(et0[0]) + b2f(et1[0]); aT.y += b2f(et0[1]) + b2f(et1[1]);
    aT.z += b2f(et0[2]) + b2f(et1[2]); aT.w += b2f(et0[3]) + b2f(et1[3]);
  }
  if (j < end) {
    int i = relIdx[j];
    ushort4v eh = *(const ushort4v*)&ent16[(size_t)th[i] * D + q * 4];
    ushort4v et = *(const ushort4v*)&ent16[(size_t)tt[i] * D + q * 4];
    aH.x += b2f(eh[0]); aH.y += b2f(eh[1]); aH.z += b2f(eh[2]); aH.w += b2f(eh[3]);
    aT.x += b2f(et[0]); aT.y += b2f(et[1]); aT.z += b2f(et[2]); aT.w += b2f(et[3]);
  }
  *(float4*)&bufH[g][q * 4] = aH;
  *(float4*)&bufT[g][q * 4] = aT;
  __syncthreads();

  int side = threadIdx.x >> 7;
  int d = threadIdx.x & 127;
  float s = 0.f;
  if (side == 0) {
#pragma unroll
    for (int g2 = 0; g2 < 8; g2++) s += bufH[g2][d];
  } else {
#pragma unroll
    for (int g2 = 0; g2 < 8; g2++) s += bufT[g2][d];
  }
  red[side][d] = s;
  __syncthreads();

  int cntv = sd.y;
  float inv = cntv ? 1.f / (float)cntv : 0.f;
  const float* w = side ? wR : wL;
  float acc = 0.f;
#pragma unroll 8
  for (int k = 0; k < D; k++) acc = fmaf(red[side][k], w[k * D + d], acc);
  float rv = fmaxf(acc * inv, 0.f);
  abR[(size_t)r * 256 + side * 128 + d] =
      (unsigned short)bfc(rv * watt[side * 128 + d]);
}

// ---------------------------------------------------------------------------
// fused edge attention + aggregation + finalize; bf16 reads incl. abR.
// ---------------------------------------------------------------------------
template <bool ENT_IS_BASE, bool WF32>
__global__ __launch_bounds__(256) void k_row_edge(
    const short* __restrict__ ent16, const short* __restrict__ base16,
    const unsigned short* __restrict__ abR,
    const int2* __restrict__ rowSD, const unsigned* __restrict__ edgeCR,
    float* __restrict__ outf, short* __restrict__ out16)
{
  int gg = blockIdx.x * 256 + threadIdx.x;
  int row = gg >> 5;
  int q = gg & 31;
  if (row >= E_N) return;
  int2 sd = rowSD[row];
  int start = sd.x;
  int end   = sd.x + sd.y;

  ushort4v bu = *(const ushort4v*)&base16[(size_t)row * D + q * 4];
  float4 b4;
  b4.x = b2f(bu[0]); b4.y = b2f(bu[1]); b4.z = b2f(bu[2]); b4.w = b2f(bu[3]);
  float4 er;
  if (ENT_IS_BASE) {
    er = b4;
  } else {
    ushort4v e = *(const ushort4v*)&ent16[(size_t)row * D + q * 4];
    er.x = b2f(e[0]); er.y = b2f(e[1]); er.z = b2f(e[2]); er.w = b2f(e[3]);
  }
  float4 acc = {0.f, 0.f, 0.f, 0.f};
  float rowsum = 0.f;

  int j = start;
  for (; j + 1 < end; j += 2) {
    unsigned cr0 = edgeCR[j];
    unsigned cr1 = edgeCR[j + 1];
    int col0 = cr0 & 0x3FFFF, rel0 = cr0 >> 18;
    int col1 = cr1 & 0x3FFFF, rel1 = cr1 >> 18;
    ushort4v e0 = *(const ushort4v*)&ent16[(size_t)col0 * D + q * 4];
    ushort4v e1 = *(const ushort4v*)&ent16[(size_t)col1 * D + q * 4];
    ushort4v a0u = *(const ushort4v*)&abR[(size_t)rel0 * 256 + q * 4];
    ushort4v c0u = *(const ushort4v*)&abR[(size_t)rel0 * 256 + 128 + q * 4];
    ushort4v a1u = *(const ushort4v*)&abR[(size_t)rel1 * 256 + q * 4];
    ushort4v c1u = *(const ushort4v*)&abR[(size_t)rel1 * 256 + 128 + q * 4];
    float4 ec0, ec1;
    ec0.x = b2f(e0[0]); ec0.y = b2f(e0[1]); ec0.z = b2f(e0[2]); ec0.w = b2f(e0[3]);
    ec1.x = b2f(e1[0]); ec1.y = b2f(e1[1]); ec1.z = b2f(e1[2]); ec1.w = b2f(e1[3]);
    float p0 = er.x * b2f(a0u[0]) + er.y * b2f(a0u[1])
             + er.z * b2f(a0u[2]) + er.w * b2f(a0u[3])
             + ec0.x * b2f(c0u[0]) + ec0.y * b2f(c0u[1])
             + ec0.z * b2f(c0u[2]) + ec0.w * b2f(c0u[3]);
    float p1 = er.x * b2f(a1u[0]) + er.y * b2f(a1u[1])
             + er.z * b2f(a1u[2]) + er.w * b2f(a1u[3])
             + ec1.x * b2f(c1u[0]) + ec1.y * b2f(c1u[1])
             + ec1.z * b2f(c1u[2]) + ec1.w * b2f(c1u[3]);
#pragma unroll
    for (int m = 16; m >= 1; m >>= 1) {
      p0 += __shfl_xor(p0, m, 64);
      p1 += __shfl_xor(p1, m, 64);
    }
    float l0 = (p0 >= 0.f) ? p0 : ALPHA_L * p0;
    float l1 = (p1 >= 0.f) ? p1 : ALPHA_L * p1;
    float att0 = __expf(-l0);
    float att1 = __expf(-l1);
    acc.x = fmaf(att0, ec0.x, acc.x); acc.y = fmaf(att0, ec0.y, acc.y);
    acc.z = fmaf(att0, ec0.z, acc.z); acc.w = fmaf(att0, ec0.w, acc.w);
    acc.x = fmaf(att1, ec1.x, acc.x); acc.y = fmaf(att1, ec1.y, acc.y);
    acc.z = fmaf(att1, ec1.z, acc.z); acc.w = fmaf(att1, ec1.w, acc.w);
    rowsum += att0 + att1;
  }
  if (j < end) {
    unsigned cr = edgeCR[j];
    int col = cr & 0x3FFFF, rel = cr >> 18;
    ushort4v e = *(const ushort4v*)&ent16[(size_t)col * D + q * 4];
    ushort4v au = *(const ushort4v*)&abR[(size_t)rel * 256 + q * 4];
    ushort4v cu = *(const ushort4v*)&abR[(size_t)rel * 256 + 128 + q * 4];
    float4 ec;
    ec.x = b2f(e[0]); ec.y = b2f(e[1]); ec.z = b2f(e[2]); ec.w = b2f(e[3]);
    float p = er.x * b2f(au[0]) + er.y * b2f(au[1])
            + er.z * b2f(au[2]) + er.w * b2f(au[3])
            + ec.x * b2f(cu[0]) + ec.y * b2f(cu[1])
            + ec.z * b2f(cu[2]) + ec.w * b2f(cu[3]);
#pragma unroll
    for (int m = 16; m >= 1; m >>= 1) p += __shfl_xor(p, m, 64);
    float lk = (p >= 0.f) ? p : ALPHA_L * p;
    float att = __expf(-lk);
    acc.x = fmaf(att, ec.x, acc.x); acc.y = fmaf(att, ec.y, acc.y);
    acc.z = fmaf(att, ec.z, acc.z); acc.w = fmaf(att, ec.w, acc.w);
    rowsum += att;
  }
  float inv = (rowsum == 0.f) ? 0.f : 1.f / rowsum;
  float4 o;
  o.x = b4.x + BETA * fmaxf(acc.x * inv, 0.f);
  o.y = b4.y + BETA * fmaxf(acc.y * inv, 0.f);
  o.z = b4.z + BETA * fmaxf(acc.z * inv, 0.f);
  o.w = b4.w + BETA * fmaxf(acc.w * inv, 0.f);
  if (WF32) {
    *(float4*)&outf[(size_t)row * D + q * 4] = o;
  } else {
    ushort4v u;
    u[0] = (unsigned short)bfc(o.x);
    u[1] = (unsigned short)bfc(o.y);
    u[2] = (unsigned short)bfc(o.z);
    u[3] = (unsigned short)bfc(o.w);
    *(ushort4v*)&out16[(size_t)row * D + q * 4] = u;
  }
}

// ---------------------------------------------------------------------------
extern "C" void kernel_launch(void* const* d_in, const int* in_sizes, int n_in,
                              void* d_out, int out_size, void* d_ws, size_t ws_size,
                              hipStream_t stream)
{
  const float* embed = (const float*)d_in[0];
  const float* wname = (const float*)d_in[1];
  const float* bname = (const float*)d_in[2];
  const float* wL    = (const float*)d_in[3];
  const float* wR    = (const float*)d_in[4];
  const float* watt  = (const float*)d_in[5];
  const int*   th    = (const int*)d_in[6];
  const int*   tr    = (const int*)d_in[7];
  const int*   tt    = (const int*)d_in[8];
  float* out = (float*)d_out;

  char* ws = (char*)d_ws;
  size_t off = 0;
  auto alloc = [&](size_t bytes) -> void* {
    void* p = ws + off;
    off = (off + bytes + 255) & ~(size_t)255;
    return p;
  };
  short*          name16 = (short*)alloc((size_t)E_N * D * 2);
  short*          gat16  = (short*)alloc((size_t)E_N * D * 2);
  unsigned short* abR    = (unsigned short*)alloc((size_t)R_N * 256 * 2);
  int*            relDeg = (int*)alloc((size_t)R_N * 4);
  int*            rowDeg = (int*)alloc((size_t)E_N * 4);
  int2*           rowSD  = (int2*)alloc((size_t)E_N * 8);
  int2*           relSD  = (int2*)alloc((size_t)R_N * 8);
  int*            rowPos = (int*)alloc((size_t)E_N * 4);
  int*            relPos = (int*)alloc((size_t)R_N * 4);
  int*            relIdx = (int*)alloc((size_t)NT * 4);
  unsigned*       edgeCR = (unsigned*)alloc((size_t)NE * 4);
  int*            ctr    = (int*)alloc((size_t)2 * 4);
  short*          WtG    = (short*)alloc((size_t)D * KP * 2);

  // prep (W pack + zero), then fused {name GEMM + histogram}
  k_prep_zero<<<ROW_BLOCKS / 4 + 1, 256, 0, stream>>>(
      wname, WtG, (int4*)relDeg, (int4*)rowDeg, ctr);
  k_name_hist<<<NAME_BLOCKS + HIST_BLOCKS, 256, 0, stream>>>(
      embed, WtG, bname, name16, th, tr, tt, relDeg, rowDeg);

  // CSR: scan-free alloc -> scatter
  k_alloc<<<ROW_BLOCKS + REL_BLOCKS, 256, 0, stream>>>(
      rowDeg, relDeg, rowSD, relSD, rowPos, relPos, ctr);
  k_scatter<<<(NT + 255) / 256, 256, 0, stream>>>(th, tr, tt, relPos, rowPos,
                                                  relIdx, edgeCR);

  // layer 1: ent = base = name16, emit gat16
  k_rel_fused<<<R_N, 256, 0, stream>>>(name16, th, tt, relIdx, relSD,
                                       wL, wR, watt, abR);
  k_row_edge<true, false><<<(E_N * 32) / 256, 256, 0, stream>>>(
      name16, name16, abR, rowSD, edgeCR, nullptr, gat16);

  // layer 2: ent = gat16, base = name16, emit f32 out
  k_rel_fused<<<R_N, 256, 0, stream>>>(gat16, th, tt, relIdx, relSD,
                                       wL, wR, watt, abR);
  k_row_edge<false, true><<<(E_N * 32) / 256, 256, 0, stream>>>(
      gat16, name16, abR, rowSD, edgeCR, out, nullptr);
}

// Round 14
// 334.789 us; speedup vs baseline: 2.2091x; 1.1064x over previous
//
#include <hip/hip_runtime.h>
#include <hip/hip_bf16.h>
#include <math.h>

#define E_N 200000
#define R_N 1000
#define D 128
#define NT 200000
#define NE (2*NT)
#define KDIM 300
#define KP 320
#define BETA 0.3f
#define ALPHA_L 0.2f
#define NAME_BLOCKS (E_N / 64)          // 3125 (64 rows per block)
#define HIST_BLOCKS 64                  // trailing LDS-histogram blocks
#define ROW_BLOCKS 782   // ceil(E_N/256)
#define REL_BLOCKS 4     // ceil(R_N/256)

typedef __attribute__((ext_vector_type(8))) short short8;
typedef __attribute__((ext_vector_type(4))) float f32x4v;
typedef __attribute__((ext_vector_type(4))) unsigned short ushort4v;

__device__ inline short bfc(float f) {
  __hip_bfloat16 b = __float2bfloat16(f);
  return *reinterpret_cast<short*>(&b);
}
__device__ inline float b2f(unsigned short u) {
  return __uint_as_float((unsigned)u << 16);
}

// ---------------------------------------------------------------------------
// Fused: zero relDeg/rowDeg/cursors + pack W -> bf16 fragment-order (KP=320)
// Element ((s*8+f)*64 + l)*8 + j = W[s*32 + (l>>4)*8 + j][f*16 + (l&15)]
// ---------------------------------------------------------------------------
__global__ __launch_bounds__(256) void k_prep_zero(
    const float* __restrict__ W, short* __restrict__ WtG,
    int4* __restrict__ relDeg, int4* __restrict__ rowDeg,
    int* __restrict__ ctr)
{
  int e = blockIdx.x * 256 + threadIdx.x;
  const int4 z = {0, 0, 0, 0};
  if (e < R_N / 4) relDeg[e] = z;
  if (e < E_N / 4) rowDeg[e] = z;
  if (e < 2) ctr[e] = 0;
  if (e < D * KP) {
    int j = e & 7;
    int l = (e >> 3) & 63;
    int fi = e >> 9;
    int s = fi >> 3, f = fi & 7;
    int k = s * 32 + (l >> 4) * 8 + j;
    int c = f * 16 + (l & 15);
    float v = (k < KDIM) ? W[(size_t)k * D + c] : 0.f;
    WtG[e] = bfc(v);
  }
}

// ---------------------------------------------------------------------------
// name16 = bf16(A[E,300] @ W + b), PLUS LDS-histogram blocks at the tail.
// A staged coalesced into XOR-swizzled LDS tile (fixes request-rate-bound
// scattered loads); W staged per-K-step; register prefetch 1 step ahead.
// Coalesced epilogue via LDS. 64 rows/block, 4 waves x 16 rows.
// ---------------------------------------------------------------------------
__global__ __launch_bounds__(256, 6) void k_name_hist(
    const float* __restrict__ A, const short* __restrict__ WtG,
    const float* __restrict__ b, short* __restrict__ out16,
    const int* __restrict__ th, const int* __restrict__ tr,
    const int* __restrict__ tt,
    int* __restrict__ relDeg, int* __restrict__ rowDeg)
{
  __shared__ __align__(16) char LB[16384];

  if (blockIdx.x >= NAME_BLOCKS) {
    // --- histogram blocks: LDS hist for relDeg (kills contention), direct
    // atomics for rowDeg (spread over 200K counters)
    int* relH = (int*)LB;
    for (int i = threadIdx.x; i < R_N; i += 256) relH[i] = 0;
    __syncthreads();
    for (int i = (blockIdx.x - NAME_BLOCKS) * 256 + threadIdx.x; i < NT;
         i += HIST_BLOCKS * 256) {
      atomicAdd(&relH[tr[i]], 1);
      atomicAdd(&rowDeg[th[i]], 1);
      atomicAdd(&rowDeg[tt[i]], 1);
    }
    __syncthreads();
    for (int i = threadIdx.x; i < R_N; i += 256) {
      int v = relH[i];
      if (v) atomicAdd(&relDeg[i], v);
    }
    return;
  }

  float* Ald = (float*)LB;             // [64][32] f32, 16B-clusters XOR-swz
  short* Wld = (short*)(LB + 8192);    // [4096] shorts (one K-step, frag order)

  const int tid = threadIdx.x;
  const int wid = tid >> 6;
  const int l   = tid & 63;
  const int lc  = l & 15;
  const int kb  = l >> 4;
  const int lc7 = lc & 7;
  const int rowbase = blockIdx.x * 64;

  f32x4v acc[8];
#pragma unroll
  for (int f = 0; f < 8; f++) acc[f] = (f32x4v){0.f, 0.f, 0.f, 0.f};

  // staging roles: thread covers rows sr and sr+32, logical 16B-cluster sc
  const int sr = tid >> 3;
  const int sc = tid & 7;
  const float* pa0 = A + (size_t)(rowbase + sr) * KDIM + sc * 4;
  const float* pa1 = A + (size_t)(rowbase + 32 + sr) * KDIM + sc * 4;
  const int swz = (sc ^ (sr & 7)) << 2;          // phys word offset in row
  float* wA0 = &Ald[sr * 32 + swz];
  float* wA1 = &Ald[(32 + sr) * 32 + swz];       // (32+sr)&7 == sr&7

  // fragment read offsets (same XOR on read side)
  const int arow = wid * 16 + lc;
  const int aoff0 = arow * 32 + (((kb * 2)     ^ lc7) << 2);
  const int aoff1 = arow * 32 + (((kb * 2 + 1) ^ lc7) << 2);

  const float4 Z4 = {0.f, 0.f, 0.f, 0.f};
  float4 aR0, aR1;
  uint4  wR0, wR1;
  // prologue: stage-regs for step 0
  aR0 = *(const float4*)(pa0);
  aR1 = *(const float4*)(pa1);
  {
    const uint4* ws = (const uint4*)WtG;
    wR0 = ws[tid];
    wR1 = ws[256 + tid];
  }

#pragma unroll
  for (int s = 0; s < 10; s++) {
    if (s) __syncthreads();              // prior compute done reading LDS
    *(float4*)wA0 = aR0;
    *(float4*)wA1 = aR1;
    ((uint4*)Wld)[tid] = wR0;
    ((uint4*)Wld)[256 + tid] = wR1;
    __syncthreads();
    // prefetch next step into regs (lands during this step's compute)
    if (s < 9) {
      if (s == 8) {                      // next = tail step (k0=288, 12 cols)
        aR0 = (sc <= 2) ? *(const float4*)(pa0 + 288) : Z4;
        aR1 = (sc <= 2) ? *(const float4*)(pa1 + 288) : Z4;
      } else {
        int k0 = 32 * (s + 1);
        aR0 = *(const float4*)(pa0 + k0);
        aR1 = *(const float4*)(pa1 + k0);
      }
      const uint4* ws = (const uint4*)(WtG + (s + 1) * 4096);
      wR0 = ws[tid];
      wR1 = ws[256 + tid];
    }
    // compute this step
    float4 a0 = *(const float4*)&Ald[aoff0];
    float4 a1 = *(const float4*)&Ald[aoff1];
    short8 af;
    af[0] = bfc(a0.x); af[1] = bfc(a0.y); af[2] = bfc(a0.z); af[3] = bfc(a0.w);
    af[4] = bfc(a1.x); af[5] = bfc(a1.y); af[6] = bfc(a1.z); af[7] = bfc(a1.w);
#pragma unroll
    for (int f = 0; f < 8; f++) {
      const short8 bf = *(const short8*)&Wld[(f * 64 + l) * 8];
      acc[f] = __builtin_amdgcn_mfma_f32_16x16x32_bf16(af, bf, acc[f], 0, 0, 0);
    }
  }

  // coalesced epilogue: acc -> LDS [64][128] bf16 -> linear short8 stores
  __syncthreads();
  float bv[8];
#pragma unroll
  for (int f = 0; f < 8; f++) bv[f] = b[f * 16 + lc];
  short* Sout = (short*)LB;
#pragma unroll
  for (int ii = 0; ii < 4; ii++) {
    int row = wid * 16 + kb * 4 + ii;
#pragma unroll
    for (int f = 0; f < 8; f++)
      Sout[row * 128 + f * 16 + lc] = bfc(acc[f][ii] + bv[f]);
  }
  __syncthreads();
  short* og = out16 + (size_t)blockIdx.x * 8192 + tid * 32;
  const short8* Ss = (const short8*)(Sout + tid * 32);
#pragma unroll
  for (int i = 0; i < 4; i++) *(short8*)(og + i * 8) = Ss[i];
}

// ---------------------------------------------------------------------------
// scan-free CSR allocation: per-block 256-wide scan + 1 atomic per block.
// blocks [0,782): rows; blocks [782,786): relations.
// ---------------------------------------------------------------------------
__global__ __launch_bounds__(256) void k_alloc(
    const int* __restrict__ rowDeg, const int* __restrict__ relDeg,
    int2* __restrict__ rowSD, int2* __restrict__ relSD,
    int* __restrict__ rowPos, int* __restrict__ relPos,
    int* __restrict__ ctr)
{
  __shared__ int sbuf[256];
  __shared__ int sbase;
  bool isRel = (blockIdx.x >= ROW_BLOCKS);
  int idx = (isRel ? (blockIdx.x - ROW_BLOCKS) : blockIdx.x) * 256 + threadIdx.x;
  int n = isRel ? R_N : E_N;
  const int* deg = isRel ? relDeg : rowDeg;
  int d = (idx < n) ? deg[idx] : 0;
  sbuf[threadIdx.x] = d;
  __syncthreads();
  for (int off = 1; off < 256; off <<= 1) {
    int v = (threadIdx.x >= off) ? sbuf[threadIdx.x - off] : 0;
    __syncthreads();
    sbuf[threadIdx.x] += v;
    __syncthreads();
  }
  int incl = sbuf[threadIdx.x];
  if (threadIdx.x == 255) sbase = atomicAdd(&ctr[isRel ? 1 : 0], incl);
  __syncthreads();
  int start = sbase + incl - d;
  if (idx < n) {
    if (isRel) { relSD[idx] = make_int2(start, d); relPos[idx] = start; }
    else       { rowSD[idx] = make_int2(start, d); rowPos[idx] = start; }
  }
}

// ---------------------------------------------------------------------------
// scatter into allocated ranges
// ---------------------------------------------------------------------------
__global__ __launch_bounds__(256) void k_scatter(
    const int* __restrict__ th, const int* __restrict__ tr,
    const int* __restrict__ tt,
    int* __restrict__ relPos, int* __restrict__ rowPos,
    int* __restrict__ relIdx, unsigned* __restrict__ edgeCR)
{
  int i = blockIdx.x * 256 + threadIdx.x;
  if (i >= NT) return;
  int h = th[i], r = tr[i], t = tt[i];
  int p = atomicAdd(&relPos[r], 1);
  relIdx[p] = i;
  int pf = atomicAdd(&rowPos[h], 1);
  edgeCR[pf] = (unsigned)t | ((unsigned)r << 18);
  int pb = atomicAdd(&rowPos[t], 1);
  edgeCR[pb] = (unsigned)h | ((unsigned)r << 18);
}

// ---------------------------------------------------------------------------
// per-relation sums (bf16 gathers, 2x unrolled) + mix GEMM -> packed bf16 abR
// ---------------------------------------------------------------------------
__global__ __launch_bounds__(256) void k_rel_fused(
    const short* __restrict__ ent16,
    const int* __restrict__ th, const int* __restrict__ tt,
    const int* __restrict__ relIdx, const int2* __restrict__ relSD,
    const float* __restrict__ wL, const float* __restrict__ wR,
    const float* __restrict__ watt,
    unsigned short* __restrict__ abR)
{
  __shared__ float bufH[8][128];
  __shared__ float bufT[8][128];
  __shared__ float red[2][128];
  int r = blockIdx.x;
  int2 sd = relSD[r];
  int start = sd.x;
  int end   = sd.x + sd.y;
  int g = threadIdx.x >> 5, q = threadIdx.x & 31;

  float4 aH = {0.f, 0.f, 0.f, 0.f}, aT = {0.f, 0.f, 0.f, 0.f};
  int j = start + g;
  for (; j + 8 < end; j += 16) {
    int i0 = relIdx[j];
    int i1 = relIdx[j + 8];
    ushort4v eh0 = *(const ushort4v*)&ent16[(size_t)th[i0] * D + q * 4];
    ushort4v et0 = *(const ushort4v*)&ent16[(size_t)tt[i0] * D + q * 4];
    ushort4v eh1 = *(const ushort4v*)&ent16[(size_t)th[i1] * D + q * 4];
    ushort4v et1 = *(const ushort4v*)&ent16[(size_t)tt[i1] * D + q * 4];
    aH.x += b2f(eh0[0]) + b2f(eh1[0]); aH.y += b2f(eh0[1]) + b2f(eh1[1]);
    aH.z += b2f(eh0[2]) + b2f(eh1[2]); aH.w += b2f(eh0[3]) + b2f(eh1[3]);
    aT.x += b2f(et0[0]) + b2f(et1[0]); aT.y += b2f(et0[1]) + b2f(et1[1]);
    aT.z += b2f(et0[2]) + b2f(et1[2]); aT.w += b2f(et0[3]) + b2f(et1[3]);
  }
  if (j < end) {
    int i = relIdx[j];
    ushort4v eh = *(const ushort4v*)&ent16[(size_t)th[i] * D + q * 4];
    ushort4v et = *(const ushort4v*)&ent16[(size_t)tt[i] * D + q * 4];
    aH.x += b2f(eh[0]); aH.y += b2f(eh[1]); aH.z += b2f(eh[2]); aH.w += b2f(eh[3]);
    aT.x += b2f(et[0]); aT.y += b2f(et[1]); aT.z += b2f(et[2]); aT.w += b2f(et[3]);
  }
  *(float4*)&bufH[g][q * 4] = aH;
  *(float4*)&bufT[g][q * 4] = aT;
  __syncthreads();

  int side = threadIdx.x >> 7;
  int d = threadIdx.x & 127;
  float s = 0.f;
  if (side == 0) {
#pragma unroll
    for (int g2 = 0; g2 < 8; g2++) s += bufH[g2][d];
  } else {
#pragma unroll
    for (int g2 = 0; g2 < 8; g2++) s += bufT[g2][d];
  }
  red[side][d] = s;
  __syncthreads();

  int cntv = sd.y;
  float inv = cntv ? 1.f / (float)cntv : 0.f;
  const float* w = side ? wR : wL;
  float acc = 0.f;
#pragma unroll 8
  for (int k = 0; k < D; k++) acc = fmaf(red[side][k], w[k * D + d], acc);
  float rv = fmaxf(acc * inv, 0.f);
  abR[(size_t)r * 256 + side * 128 + d] =
      (unsigned short)bfc(rv * watt[side * 128 + d]);
}

// ---------------------------------------------------------------------------
// fused edge attention + aggregation + finalize; bf16 reads incl. abR.
// ---------------------------------------------------------------------------
template <bool ENT_IS_BASE, bool WF32>
__global__ __launch_bounds__(256) void k_row_edge(
    const short* __restrict__ ent16, const short* __restrict__ base16,
    const unsigned short* __restrict__ abR,
    const int2* __restrict__ rowSD, const unsigned* __restrict__ edgeCR,
    float* __restrict__ outf, short* __restrict__ out16)
{
  int gg = blockIdx.x * 256 + threadIdx.x;
  int row = gg >> 5;
  int q = gg & 31;
  if (row >= E_N) return;
  int2 sd = rowSD[row];
  int start = sd.x;
  int end   = sd.x + sd.y;

  ushort4v bu = *(const ushort4v*)&base16[(size_t)row * D + q * 4];
  float4 b4;
  b4.x = b2f(bu[0]); b4.y = b2f(bu[1]); b4.z = b2f(bu[2]); b4.w = b2f(bu[3]);
  float4 er;
  if (ENT_IS_BASE) {
    er = b4;
  } else {
    ushort4v e = *(const ushort4v*)&ent16[(size_t)row * D + q * 4];
    er.x = b2f(e[0]); er.y = b2f(e[1]); er.z = b2f(e[2]); er.w = b2f(e[3]);
  }
  float4 acc = {0.f, 0.f, 0.f, 0.f};
  float rowsum = 0.f;

  int j = start;
  for (; j + 1 < end; j += 2) {
    unsigned cr0 = edgeCR[j];
    unsigned cr1 = edgeCR[j + 1];
    int col0 = cr0 & 0x3FFFF, rel0 = cr0 >> 18;
    int col1 = cr1 & 0x3FFFF, rel1 = cr1 >> 18;
    ushort4v e0 = *(const ushort4v*)&ent16[(size_t)col0 * D + q * 4];
    ushort4v e1 = *(const ushort4v*)&ent16[(size_t)col1 * D + q * 4];
    ushort4v a0u = *(const ushort4v*)&abR[(size_t)rel0 * 256 + q * 4];
    ushort4v c0u = *(const ushort4v*)&abR[(size_t)rel0 * 256 + 128 + q * 4];
    ushort4v a1u = *(const ushort4v*)&abR[(size_t)rel1 * 256 + q * 4];
    ushort4v c1u = *(const ushort4v*)&abR[(size_t)rel1 * 256 + 128 + q * 4];
    float4 ec0, ec1;
    ec0.x = b2f(e0[0]); ec0.y = b2f(e0[1]); ec0.z = b2f(e0[2]); ec0.w = b2f(e0[3]);
    ec1.x = b2f(e1[0]); ec1.y = b2f(e1[1]); ec1.z = b2f(e1[2]); ec1.w = b2f(e1[3]);
    float p0 = er.x * b2f(a0u[0]) + er.y * b2f(a0u[1])
             + er.z * b2f(a0u[2]) + er.w * b2f(a0u[3])
             + ec0.x * b2f(c0u[0]) + ec0.y * b2f(c0u[1])
             + ec0.z * b2f(c0u[2]) + ec0.w * b2f(c0u[3]);
    float p1 = er.x * b2f(a1u[0]) + er.y * b2f(a1u[1])
             + er.z * b2f(a1u[2]) + er.w * b2f(a1u[3])
             + ec1.x * b2f(c1u[0]) + ec1.y * b2f(c1u[1])
             + ec1.z * b2f(c1u[2]) + ec1.w * b2f(c1u[3]);
#pragma unroll
    for (int m = 16; m >= 1; m >>= 1) {
      p0 += __shfl_xor(p0, m, 64);
      p1 += __shfl_xor(p1, m, 64);
    }
    float l0 = (p0 >= 0.f) ? p0 : ALPHA_L * p0;
    float l1 = (p1 >= 0.f) ? p1 : ALPHA_L * p1;
    float att0 = __expf(-l0);
    float att1 = __expf(-l1);
    acc.x = fmaf(att0, ec0.x, acc.x); acc.y = fmaf(att0, ec0.y, acc.y);
    acc.z = fmaf(att0, ec0.z, acc.z); acc.w = fmaf(att0, ec0.w, acc.w);
    acc.x = fmaf(att1, ec1.x, acc.x); acc.y = fmaf(att1, ec1.y, acc.y);
    acc.z = fmaf(att1, ec1.z, acc.z); acc.w = fmaf(att1, ec1.w, acc.w);
    rowsum += att0 + att1;
  }
  if (j < end) {
    unsigned cr = edgeCR[j];
    int col = cr & 0x3FFFF, rel = cr >> 18;
    ushort4v e = *(const ushort4v*)&ent16[(size_t)col * D + q * 4];
    ushort4v au = *(const ushort4v*)&abR[(size_t)rel * 256 + q * 4];
    ushort4v cu = *(const ushort4v*)&abR[(size_t)rel * 256 + 128 + q * 4];
    float4 ec;
    ec.x = b2f(e[0]); ec.y = b2f(e[1]); ec.z = b2f(e[2]); ec.w = b2f(e[3]);
    float p = er.x * b2f(au[0]) + er.y * b2f(au[1])
            + er.z * b2f(au[2]) + er.w * b2f(au[3])
            + ec.x * b2f(cu[0]) + ec.y * b2f(cu[1])
            + ec.z * b2f(cu[2]) + ec.w * b2f(cu[3]);
#pragma unroll
    for (int m = 16; m >= 1; m >>= 1) p += __shfl_xor(p, m, 64);
    float lk = (p >= 0.f) ? p : ALPHA_L * p;
    float att = __expf(-lk);
    acc.x = fmaf(att, ec.x, acc.x); acc.y = fmaf(att, ec.y, acc.y);
    acc.z = fmaf(att, ec.z, acc.z); acc.w = fmaf(att, ec.w, acc.w);
    rowsum += att;
  }
  float inv = (rowsum == 0.f) ? 0.f : 1.f / rowsum;
  float4 o;
  o.x = b4.x + BETA * fmaxf(acc.x * inv, 0.f);
  o.y = b4.y + BETA * fmaxf(acc.y * inv, 0.f);
  o.z = b4.z + BETA * fmaxf(acc.z * inv, 0.f);
  o.w = b4.w + BETA * fmaxf(acc.w * inv, 0.f);
  if (WF32) {
    *(float4*)&outf[(size_t)row * D + q * 4] = o;
  } else {
    ushort4v u;
    u[0] = (unsigned short)bfc(o.x);
    u[1] = (unsigned short)bfc(o.y);
    u[2] = (unsigned short)bfc(o.z);
    u[3] = (unsigned short)bfc(o.w);
    *(ushort4v*)&out16[(size_t)row * D + q * 4] = u;
  }
}

// ---------------------------------------------------------------------------
extern "C" void kernel_launch(void* const* d_in, const int* in_sizes, int n_in,
                              void* d_out, int out_size, void* d_ws, size_t ws_size,
                              hipStream_t stream)
{
  const float* embed = (const float*)d_in[0];
  const float* wname = (const float*)d_in[1];
  const float* bname = (const float*)d_in[2];
  const float* wL    = (const float*)d_in[3];
  const float* wR    = (const float*)d_in[4];
  const float* watt  = (const float*)d_in[5];
  const int*   th    = (const int*)d_in[6];
  const int*   tr    = (const int*)d_in[7];
  const int*   tt    = (const int*)d_in[8];
  float* out = (float*)d_out;

  char* ws = (char*)d_ws;
  size_t off = 0;
  auto alloc = [&](size_t bytes) -> void* {
    void* p = ws + off;
    off = (off + bytes + 255) & ~(size_t)255;
    return p;
  };
  short*          name16 = (short*)alloc((size_t)E_N * D * 2);
  short*          gat16  = (short*)alloc((size_t)E_N * D * 2);
  unsigned short* abR    = (unsigned short*)alloc((size_t)R_N * 256 * 2);
  int*            relDeg = (int*)alloc((size_t)R_N * 4);
  int*            rowDeg = (int*)alloc((size_t)E_N * 4);
  int2*           rowSD  = (int2*)alloc((size_t)E_N * 8);
  int2*           relSD  = (int2*)alloc((size_t)R_N * 8);
  int*            rowPos = (int*)alloc((size_t)E_N * 4);
  int*            relPos = (int*)alloc((size_t)R_N * 4);
  int*            relIdx = (int*)alloc((size_t)NT * 4);
  unsigned*       edgeCR = (unsigned*)alloc((size_t)NE * 4);
  int*            ctr    = (int*)alloc((size_t)2 * 4);
  short*          WtG    = (short*)alloc((size_t)D * KP * 2);

  // prep (W pack + zero), then fused {name GEMM + histogram}
  k_prep_zero<<<ROW_BLOCKS / 4 + 1, 256, 0, stream>>>(
      wname, WtG, (int4*)relDeg, (int4*)rowDeg, ctr);
  k_name_hist<<<NAME_BLOCKS + HIST_BLOCKS, 256, 0, stream>>>(
      embed, WtG, bname, name16, th, tr, tt, relDeg, rowDeg);

  // CSR: scan-free alloc -> scatter
  k_alloc<<<ROW_BLOCKS + REL_BLOCKS, 256, 0, stream>>>(
      rowDeg, relDeg, rowSD, relSD, rowPos, relPos, ctr);
  k_scatter<<<(NT + 255) / 256, 256, 0, stream>>>(th, tr, tt, relPos, rowPos,
                                                  relIdx, edgeCR);

  // layer 1: ent = base = name16, emit gat16
  k_rel_fused<<<R_N, 256, 0, stream>>>(name16, th, tt, relIdx, relSD,
                                       wL, wR, watt, abR);
  k_row_edge<true, false><<<(E_N * 32) / 256, 256, 0, stream>>>(
      name16, name16, abR, rowSD, edgeCR, nullptr, gat16);

  // layer 2: ent = gat16, base = name16, emit f32 out
  k_rel_fused<<<R_N, 256, 0, stream>>>(gat16, th, tt, relIdx, relSD,
                                       wL, wR, watt, abR);
  k_row_edge<false, true><<<(E_N * 32) / 256, 256, 0, stream>>>(
      gat16, name16, abR, rowSD, edgeCR, out, nullptr);
}